// Round 7
// baseline (92.546 us; speedup 1.0000x reference)
//
#include <hip/hip_runtime.h>
#include <cstdint>

typedef unsigned short u16;
using short8 = __attribute__((ext_vector_type(8))) short;
using f32x4  = __attribute__((ext_vector_type(4))) float;

#define T1 512
#define T2 832
#define NH 16
#define NPLOC 448

__device__ __forceinline__ u16 f2b(float f){
  union { float f; uint32_t u; } c; c.f = f;
  uint32_t u = c.u;
  u += 0x7fffu + ((u >> 16) & 1u);   // RNE bf16
  return (u16)(u >> 16);
}
__device__ __forceinline__ float b2f(u16 b){
  union { uint32_t u; float f; } c; c.u = (uint32_t)b << 16; return c.f;
}
__device__ __forceinline__ void async16(const void* g, void* l){
  __builtin_amdgcn_global_load_lds(
      (const __attribute__((address_space(1))) unsigned int*)g,
      (__attribute__((address_space(3))) unsigned int*)l, 16, 0, 0);
}

// ---------------- fused f32 -> bf16 convert (one launch) ----------------
struct CvtSeg { const float* src; u16* dst; int nblk; };
struct CvtArgs { CvtSeg s[9]; };

__global__ __launch_bounds__(256) void cvt_all(CvtArgs a){
  int rel = blockIdx.x, seg = 0;
  while (rel >= a.s[seg].nblk){ rel -= a.s[seg].nblk; ++seg; }
  int i = rel * 256 + threadIdx.x;
  float4 v = ((const float4*)a.s[seg].src)[i];
  uint64_t p = (uint64_t)f2b(v.x) | ((uint64_t)f2b(v.y) << 16)
             | ((uint64_t)f2b(v.z) << 32) | ((uint64_t)f2b(v.w) << 48);
  *(uint64_t*)(a.s[seg].dst + (size_t)i * 4) = p;
}

// ---------------- triple-buffered single-barrier GEMM core, 128x128 ----------------
// Per step: vmcnt(4) -> s_barrier -> ds_read (compiler fine-grained lgkm) ->
// stage(tile i+2 into buf[(i+2)%3]) -> MFMA (overlaps read drain) -> lgkmcnt(0).
// Buffer staged at step i was last read at step i-1: readers' lgkmcnt(0) precedes
// this step's barrier, which precedes the stage -> no race. vmcnt BEFORE barrier
// makes cross-wave load completeness transitive.
__device__ __forceinline__ void gemm_core128(const u16* __restrict__ A, const u16* __restrict__ W,
    int m0, int n0, int tid, f32x4 acc[4][4])
{
  __shared__ __align__(16) u16 As0[4096];
  __shared__ __align__(16) u16 As1[4096];
  __shared__ __align__(16) u16 As2[4096];
  __shared__ __align__(16) u16 Bs0[4096];
  __shared__ __align__(16) u16 Bs1[4096];
  __shared__ __align__(16) u16 Bs2[4096];

  int lane = tid & 63, w = tid >> 6;
  int wr = w >> 1, wc = w & 1;
  const int lr = lane & 15, g = lane >> 4;
  const int sslot = (g ^ ((lr >> 1) & 3)) * 8;           // read-side swizzled slot

  int r = tid >> 2;
  int ssl = ((tid & 3) ^ ((tid >> 3) & 3)) * 8;          // stage-source swizzled slot
  const u16* Asrc = A + (size_t)(m0 + r) * 1024 + ssl;
  const u16* Bsrc = W + (size_t)(n0 + r) * 1024 + ssl;

  auto stage = [&](int k0, u16* as, u16* bs){
    async16(Asrc + k0,         as + tid*8);
    async16(Asrc + 65536 + k0, as + 2048 + tid*8);       // A rows +64
    async16(Bsrc + k0,         bs + tid*8);
    async16(Bsrc + 65536 + k0, bs + 2048 + tid*8);       // B rows +64
  };

  auto step = [&](const u16* as, const u16* bs, u16* sas, u16* sbs,
                  int kstage, bool do_stage, bool last){
    if (last) asm volatile("s_waitcnt vmcnt(0)" ::: "memory");
    else      asm volatile("s_waitcnt vmcnt(4)" ::: "memory");  // own tile-i loads done
    __builtin_amdgcn_sched_barrier(0);
    __builtin_amdgcn_s_barrier();                         // all waves' portions resident
    __builtin_amdgcn_sched_barrier(0);
    short8 a[4], b[4];
    #pragma unroll
    for (int m = 0; m < 4; ++m) a[m] = *(const short8*)&as[(wr*64 + m*16 + lr)*32 + sslot];
    #pragma unroll
    for (int n = 0; n < 4; ++n) b[n] = *(const short8*)&bs[(wc*64 + n*16 + lr)*32 + sslot];
    if (do_stage) stage(kstage, sas, sbs);
    __builtin_amdgcn_s_setprio(1);
    #pragma unroll
    for (int m = 0; m < 4; ++m)
      #pragma unroll
      for (int n = 0; n < 4; ++n)
        acc[m][n] = __builtin_amdgcn_mfma_f32_16x16x32_bf16(a[m], b[n], acc[m][n], 0, 0, 0);
    __builtin_amdgcn_s_setprio(0);
    asm volatile("s_waitcnt lgkmcnt(0)" ::: "memory");    // reads done before next-step stage
    __builtin_amdgcn_sched_barrier(0);
  };

  stage(0,  As0, Bs0);
  stage(32, As1, Bs1);
  for (int s = 0; s < 30; s += 3){
    step(As0, Bs0, As2, Bs2, (s+2)*32, true, false);
    step(As1, Bs1, As0, Bs0, (s+3)*32, true, false);
    step(As2, Bs2, As1, Bs1, (s+4)*32, true, false);
  }
  step(As0, Bs0, As2, Bs2, 0, false, false);             // tile 30
  step(As1, Bs1, As2, Bs2, 0, false, true);              // tile 31
}

// ---------------- same schedule, 64x128 tile (for gemm_out: 256 blocks) ----------------
__device__ __forceinline__ void gemm_core64(const u16* __restrict__ A, const u16* __restrict__ W,
    int m0, int n0, int tid, f32x4 acc[4][2])
{
  __shared__ __align__(16) u16 As0[2048];
  __shared__ __align__(16) u16 As1[2048];
  __shared__ __align__(16) u16 As2[2048];
  __shared__ __align__(16) u16 Bs0[4096];
  __shared__ __align__(16) u16 Bs1[4096];
  __shared__ __align__(16) u16 Bs2[4096];

  int lane = tid & 63, wc = tid >> 6;
  const int lr = lane & 15, g = lane >> 4;
  const int sslot = (g ^ ((lr >> 1) & 3)) * 8;

  int r = tid >> 2;
  int ssl = ((tid & 3) ^ ((tid >> 3) & 3)) * 8;
  const u16* Asrc = A + (size_t)(m0 + r) * 1024 + ssl;
  const u16* Bsrc = W + (size_t)(n0 + r) * 1024 + ssl;

  auto stage = [&](int k0, u16* as, u16* bs){
    async16(Asrc + k0,         as + tid*8);
    async16(Bsrc + k0,         bs + tid*8);
    async16(Bsrc + 65536 + k0, bs + 2048 + tid*8);
  };

  auto step = [&](const u16* as, const u16* bs, u16* sas, u16* sbs,
                  int kstage, bool do_stage, bool last){
    if (last) asm volatile("s_waitcnt vmcnt(0)" ::: "memory");
    else      asm volatile("s_waitcnt vmcnt(3)" ::: "memory");
    __builtin_amdgcn_sched_barrier(0);
    __builtin_amdgcn_s_barrier();
    __builtin_amdgcn_sched_barrier(0);
    short8 a[4], b[2];
    #pragma unroll
    for (int m = 0; m < 4; ++m) a[m] = *(const short8*)&as[(m*16 + lr)*32 + sslot];
    #pragma unroll
    for (int n = 0; n < 2; ++n) b[n] = *(const short8*)&bs[(wc*32 + n*16 + lr)*32 + sslot];
    if (do_stage) stage(kstage, sas, sbs);
    __builtin_amdgcn_s_setprio(1);
    #pragma unroll
    for (int m = 0; m < 4; ++m)
      #pragma unroll
      for (int n = 0; n < 2; ++n)
        acc[m][n] = __builtin_amdgcn_mfma_f32_16x16x32_bf16(a[m], b[n], acc[m][n], 0, 0, 0);
    __builtin_amdgcn_s_setprio(0);
    asm volatile("s_waitcnt lgkmcnt(0)" ::: "memory");
    __builtin_amdgcn_sched_barrier(0);
  };

  stage(0,  As0, Bs0);
  stage(32, As1, Bs1);
  for (int s = 0; s < 30; s += 3){
    step(As0, Bs0, As2, Bs2, (s+2)*32, true, false);
    step(As1, Bs1, As0, Bs0, (s+3)*32, true, false);
    step(As2, Bs2, As1, Bs1, (s+4)*32, true, false);
  }
  step(As0, Bs0, As2, Bs2, 0, false, false);
  step(As1, Bs1, As2, Bs2, 0, false, true);
}

// ---------------- fused q/k/v/pos projection GEMMs (576 blocks) ----------------
struct G4Args {
  const u16 *q, *k, *v, *p;
  const u16 *Wq, *Wk, *Wv, *Wp;
  const float *bq, *bk, *bv, *pbu, *pbv;
  u16 *qu, *qv2, *katt, *vatt, *patt;
  float *cache;
};

__global__ __launch_bounds__(256, 3) void gemm4(G4Args ga){
  int bid0 = blockIdx.x;
  int bid = (bid0 & 7) * 72 + (bid0 >> 3);   // XCD swizzle (576 = 8*72)
  int tid = threadIdx.x;
  int mode, mb; const u16 *A, *W;
  if (bid < 128)      { mode = 0; mb = bid >> 3;         A = ga.q; W = ga.Wq; }
  else if (bid < 336) { mode = 1; mb = (bid - 128) >> 3; A = ga.k; W = ga.Wk; }
  else if (bid < 544) { mode = 2; mb = (bid - 336) >> 3; A = ga.v; W = ga.Wv; }
  else                { mode = 3; mb = (bid - 544) >> 3; A = ga.p; W = ga.Wp; }
  int m0 = mb * 128, n0 = (bid & 7) * 128;
  f32x4 acc[4][4] = {};
  gemm_core128(A, W, m0, n0, tid, acc);

  int lane = tid & 63, w = tid >> 6;
  int wr = w >> 1, wc = w & 1;
  const int lr = lane & 15, g = lane >> 4;
  #pragma unroll
  for (int m = 0; m < 4; ++m){
    #pragma unroll
    for (int n = 0; n < 4; ++n){
      #pragma unroll
      for (int j = 0; j < 4; ++j){
        int row = m0 + wr*64 + m*16 + g*4 + j;
        int col = n0 + wc*64 + n*16 + lr;
        float vv = acc[m][n][j];
        if (mode == 0){
          vv += ga.bq[col];
          int h = col >> 6, d = col & 63, b_ = row >> 9, t = row & 511;
          size_t o = ((size_t)((b_*NH + h)*T1 + t))*64 + d;
          ga.qu [o] = f2b(vv + ga.pbu[col]);
          ga.qv2[o] = f2b(vv + ga.pbv[col]);
        } else if (mode == 1 || mode == 2){
          vv += (mode == 1 ? ga.bk : ga.bv)[col];
          int h = col >> 6, d = col & 63;
          int b_ = row / T2, t2 = row - b_*T2;
          size_t base = (size_t)(b_*NH + h)*T2 + t2;
          ga.cache[base*128 + (mode == 2 ? 64 : 0) + d] = vv;
          (mode == 1 ? ga.katt : ga.vatt)[base*64 + d] = f2b(vv);
        } else {
          if (row < NPLOC){
            int h = col >> 6, d = col & 63;
            ga.patt[((size_t)h*NPLOC + row)*64 + d] = f2b(vv);
          }
        }
      }
    }
  }
}

// ---------------- output GEMM (256 blocks, 64x128 tile) ----------------
__global__ __launch_bounds__(256, 4) void gemm_out(const u16* __restrict__ A, const u16* __restrict__ W,
                                                   const float* __restrict__ bias, float* __restrict__ out){
  int bid0 = blockIdx.x;
  int bid = (bid0 & 7) * 32 + (bid0 >> 3);   // 256 = 8*32
  int m0 = (bid >> 3) * 64, n0 = (bid & 7) * 128;
  int tid = threadIdx.x;
  f32x4 acc[4][2] = {};
  gemm_core64(A, W, m0, n0, tid, acc);
  int lane = tid & 63, wc = tid >> 6;
  const int lr = lane & 15, g = lane >> 4;
  #pragma unroll
  for (int m = 0; m < 4; ++m)
    #pragma unroll
    for (int n = 0; n < 2; ++n)
      #pragma unroll
      for (int j = 0; j < 4; ++j){
        int row = m0 + m*16 + g*4 + j;
        int col = n0 + wc*32 + n*16 + lr;
        out[(size_t)row*1024 + col] = acc[m][n][j] + bias[col];
      }
}

// ---------------- attention (unchanged) ----------------
__global__ __launch_bounds__(256, 2) void attn_v2(
    const u16* __restrict__ qu, const u16* __restrict__ qv,
    const u16* __restrict__ katt, const u16* __restrict__ vatt,
    const u16* __restrict__ patt, u16* __restrict__ xout)
{
  __shared__ __align__(16) u16 SB[64*384];    // 49152 B
  __shared__ __align__(16) u16 STG[14336];    // 28672 B staging
  int tid = threadIdx.x, lane = tid & 63, w = tid >> 6;
  int bid0 = blockIdx.x;
  int bid = (bid0 & 7) * 64 + (bid0 >> 3);    // XCD swizzle (512 = 8*64)
  int c = bid & 7, h = (bid >> 3) & 15, b = bid >> 7;
  int bh = b*NH + h;
  const int lr = lane & 15, g = lane >> 4, lk = g * 8;

  auto sb_off = [&](int r, int cc) -> uint32_t {
    return ((uint32_t)(r*384 + cc)*2) ^ ((uint32_t)(r & 15) << 4);
  };
  auto stg_swz = [&](uint32_t o) -> uint32_t { return o ^ (((o >> 7) & 7u) << 4); };
  auto vt_off = [&](int d, int kk) -> uint32_t {
    return ((uint32_t)(d*192 + kk)*2) ^ ((uint32_t)(((d & 7) ^ ((d >> 3) & 7))) << 4);
  };

  int qrow = 16*w + lr;
  const u16* qub = qu + ((size_t)bh*T1 + c*64 + qrow)*64;
  const u16* qvb = qv + ((size_t)bh*T1 + c*64 + qrow)*64;
  short8 qu0 = *(const short8*)(qub + lk);
  short8 qu1 = *(const short8*)(qub + 32 + lk);
  short8 qv0 = *(const short8*)(qvb + lk);
  short8 qv1 = *(const short8*)(qvb + 32 + lk);

  // ---- BD ----
  const char* psrc = (const char*)(patt + (size_t)h*NPLOC*64);
  for (int pc = 0; pc < 2; ++pc){
    #pragma unroll
    for (int i = 0; i < 7; ++i){
      uint32_t o = (uint32_t)(i*256 + tid)*16;
      async16(psrc + pc*28672 + stg_swz(o), (char*)STG + o);
    }
    __syncthreads();
    for (int nt = 0; nt < 14; ++nt){
      uint32_t bo = (uint32_t)((nt*16 + lr)*64)*2;
      short8 b0 = *(const short8*)((const char*)STG + stg_swz(bo + lk*2));
      short8 b1 = *(const short8*)((const char*)STG + stg_swz(bo + (32 + lk)*2));
      f32x4 acc = {0.f,0.f,0.f,0.f};
      __builtin_amdgcn_s_setprio(1);
      acc = __builtin_amdgcn_mfma_f32_16x16x32_bf16(qv0, b0, acc, 0, 0, 0);
      acc = __builtin_amdgcn_mfma_f32_16x16x32_bf16(qv1, b1, acc, 0, 0, 0);
      __builtin_amdgcn_s_setprio(0);
      int nl = pc*224 + nt*16 + lr;
      #pragma unroll
      for (int j = 0; j < 4; ++j){
        int r = 16*w + g*4 + j;
        int jj = nl + r - 63;
        if (jj >= 0 && jj < 384) *(u16*)((char*)SB + sb_off(r, jj)) = f2b(acc[j]);
      }
    }
    __syncthreads();
  }

  // ---- AC ----
  const char* ksrc = (const char*)(katt + ((size_t)bh*T2 + c*64)*64);
  f32x4 accs[24];
  #pragma unroll
  for (int t = 0; t < 24; ++t) accs[t] = (f32x4){0.f,0.f,0.f,0.f};
  #pragma unroll
  for (int kc = 0; kc < 2; ++kc){
    #pragma unroll
    for (int i = 0; i < 6; ++i){
      uint32_t o = (uint32_t)(i*256 + tid)*16;
      async16(ksrc + kc*24576 + stg_swz(o), (char*)STG + o);
    }
    __syncthreads();
    #pragma unroll
    for (int nt = 0; nt < 12; ++nt){
      uint32_t bo = (uint32_t)((nt*16 + lr)*64)*2;
      short8 b0 = *(const short8*)((const char*)STG + stg_swz(bo + lk*2));
      short8 b1 = *(const short8*)((const char*)STG + stg_swz(bo + (32 + lk)*2));
      int t = kc*12 + nt;
      __builtin_amdgcn_s_setprio(1);
      accs[t] = __builtin_amdgcn_mfma_f32_16x16x32_bf16(qu0, b0, accs[t], 0, 0, 0);
      accs[t] = __builtin_amdgcn_mfma_f32_16x16x32_bf16(qu1, b1, accs[t], 0, 0, 0);
      __builtin_amdgcn_s_setprio(0);
    }
    __syncthreads();
  }

  // ---- add bd, softmax in registers, P back to SB ----
  #pragma unroll
  for (int t = 0; t < 24; ++t)
    #pragma unroll
    for (int j = 0; j < 4; ++j){
      int r = 16*w + g*4 + j, cc = t*16 + lr;
      accs[t][j] += b2f(*(const u16*)((const char*)SB + sb_off(r, cc)));
    }
  float mx[4] = {-1e30f,-1e30f,-1e30f,-1e30f};
  #pragma unroll
  for (int t = 0; t < 24; ++t)
    #pragma unroll
    for (int j = 0; j < 4; ++j) mx[j] = fmaxf(mx[j], accs[t][j]);
  #pragma unroll
  for (int j = 0; j < 4; ++j){
    mx[j] = fmaxf(mx[j], __shfl_xor(mx[j], 1));
    mx[j] = fmaxf(mx[j], __shfl_xor(mx[j], 2));
    mx[j] = fmaxf(mx[j], __shfl_xor(mx[j], 4));
    mx[j] = fmaxf(mx[j], __shfl_xor(mx[j], 8));
  }
  float sm[4] = {0.f,0.f,0.f,0.f};
  #pragma unroll
  for (int t = 0; t < 24; ++t)
    #pragma unroll
    for (int j = 0; j < 4; ++j){
      accs[t][j] = __expf((accs[t][j] - mx[j]) * 0.125f);
      sm[j] += accs[t][j];
    }
  #pragma unroll
  for (int j = 0; j < 4; ++j){
    sm[j] += __shfl_xor(sm[j], 1);
    sm[j] += __shfl_xor(sm[j], 2);
    sm[j] += __shfl_xor(sm[j], 4);
    sm[j] += __shfl_xor(sm[j], 8);
    sm[j] = 1.f / sm[j];
  }
  #pragma unroll
  for (int t = 0; t < 24; ++t)
    #pragma unroll
    for (int j = 0; j < 4; ++j){
      int r = 16*w + g*4 + j, cc = t*16 + lr;
      *(u16*)((char*)SB + sb_off(r, cc)) = f2b(accs[t][j] * sm[j]);
    }
  __syncthreads();

  // ---- PV ----
  f32x4 acco[4] = {};
  #pragma unroll
  for (int vc = 0; vc < 2; ++vc){
    if (vc) __syncthreads();
    const u16* vb = vatt + ((size_t)bh*T2 + c*64 + vc*192)*64;
    #pragma unroll
    for (int i = 0; i < 6; ++i){
      int e = (i*256 + tid)*8;
      int kk = e >> 6, d0 = e & 63;
      uint4 vv4 = *(const uint4*)(vb + (size_t)kk*64 + d0);
      u16 uu[8] = { (u16)(vv4.x & 0xffff), (u16)(vv4.x >> 16), (u16)(vv4.y & 0xffff), (u16)(vv4.y >> 16),
                    (u16)(vv4.z & 0xffff), (u16)(vv4.z >> 16), (u16)(vv4.w & 0xffff), (u16)(vv4.w >> 16) };
      #pragma unroll
      for (int j = 0; j < 8; ++j)
        *(u16*)((char*)STG + vt_off(d0 + j, kk)) = uu[j];
    }
    __syncthreads();
    #pragma unroll
    for (int kt = 0; kt < 6; ++kt){
      short8 a = *(const short8*)((const char*)SB + sb_off(16*w + lr, vc*192 + kt*32 + lk));
      __builtin_amdgcn_s_setprio(1);
      #pragma unroll
      for (int n = 0; n < 4; ++n){
        short8 bb = *(const short8*)((const char*)STG + vt_off(n*16 + lr, kt*32 + lk));
        acco[n] = __builtin_amdgcn_mfma_f32_16x16x32_bf16(a, bb, acco[n], 0, 0, 0);
      }
      __builtin_amdgcn_s_setprio(0);
    }
  }

  #pragma unroll
  for (int n = 0; n < 4; ++n)
    #pragma unroll
    for (int j = 0; j < 4; ++j){
      int r = 16*w + g*4 + j;
      int t = c*64 + r, d = n*16 + lr;
      xout[((size_t)b*T1 + t)*1024 + h*64 + d] = f2b(acco[n][j]);
    }
}

// ---------------- launch ----------------
extern "C" void kernel_launch(void* const* d_in, const int* in_sizes, int n_in,
                              void* d_out, int out_size, void* d_ws, size_t ws_size,
                              hipStream_t stream)
{
  const float* query = (const float*)d_in[0];
  const float* key   = (const float*)d_in[1];
  const float* value = (const float*)d_in[2];
  const float* pos   = (const float*)d_in[3];
  const float* Wq  = (const float*)d_in[4];
  const float* bq  = (const float*)d_in[5];
  const float* Wk  = (const float*)d_in[6];
  const float* bk  = (const float*)d_in[7];
  const float* Wv  = (const float*)d_in[8];
  const float* bv  = (const float*)d_in[9];
  const float* Wp  = (const float*)d_in[10];
  const float* Wo  = (const float*)d_in[11];
  const float* bo  = (const float*)d_in[12];
  const float* pbu = (const float*)d_in[13];
  const float* pbv = (const float*)d_in[14];

  float* out   = (float*)d_out;
  float* cache = out + 2097152;

  u16* ws     = (u16*)d_ws;
  u16* q_bf   = ws;
  u16* key_bf = ws + 2097152;
  u16* val_bf = ws + 5505024;
  u16* pos_bf = ws + 8912896;
  u16* Wq_bf  = ws + 9437184;
  u16* Wk_bf  = ws + 10485760;
  u16* Wv_bf  = ws + 11534336;
  u16* Wp_bf  = ws + 12582912;
  u16* Wo_bf  = ws + 13631488;
  u16* qu_bf  = ws + 14680064;
  u16* qv_bf  = ws + 16777216;
  u16* katt   = ws + 18874368;
  u16* vatt   = ws + 22282240;
  u16* patt   = ws + 25690112;
  u16* x_bf   = ws + 26148864;

  CvtArgs ca;
  ca.s[0] = { query,            q_bf,   2048 };
  ca.s[1] = { key,              key_bf, 3328 };
  ca.s[2] = { value,            val_bf, 3328 };
  ca.s[3] = { Wq,               Wq_bf,  1024 };
  ca.s[4] = { Wk,               Wk_bf,  1024 };
  ca.s[5] = { Wv,               Wv_bf,  1024 };
  ca.s[6] = { Wp,               Wp_bf,  1024 };
  ca.s[7] = { Wo,               Wo_bf,  1024 };
  ca.s[8] = { pos + 448*1024,   pos_bf, 448 };
  cvt_all<<<14272, 256, 0, stream>>>(ca);

  G4Args ga;
  ga.q = q_bf; ga.k = key_bf; ga.v = val_bf; ga.p = pos_bf;
  ga.Wq = Wq_bf; ga.Wk = Wk_bf; ga.Wv = Wv_bf; ga.Wp = Wp_bf;
  ga.bq = bq; ga.bk = bk; ga.bv = bv; ga.pbu = pbu; ga.pbv = pbv;
  ga.qu = qu_bf; ga.qv2 = qv_bf; ga.katt = katt; ga.vatt = vatt; ga.patt = patt;
  ga.cache = cache;
  gemm4<<<576, 256, 0, stream>>>(ga);

  attn_v2<<<512, 256, 0, stream>>>(qu_bf, qv_bf, katt, vatt, patt, x_bf);

  gemm_out<<<256, 256, 0, stream>>>(x_bf, Wo_bf, bo, out);
}

// Round 8
// 89.844 us; speedup vs baseline: 1.0301x; 1.0301x over previous
//
#include <hip/hip_runtime.h>
#include <cstdint>

typedef unsigned short u16;
using short8 = __attribute__((ext_vector_type(8))) short;
using f32x4  = __attribute__((ext_vector_type(4))) float;

#define T1 512
#define T2 832
#define NH 16
#define NPLOC 448

__device__ __forceinline__ u16 f2b(float f){
  union { float f; uint32_t u; } c; c.f = f;
  uint32_t u = c.u;
  u += 0x7fffu + ((u >> 16) & 1u);   // RNE bf16
  return (u16)(u >> 16);
}
__device__ __forceinline__ float b2f(u16 b){
  union { uint32_t u; float f; } c; c.u = (uint32_t)b << 16; return c.f;
}
__device__ __forceinline__ void async16(const void* g, void* l){
  __builtin_amdgcn_global_load_lds(
      (const __attribute__((address_space(1))) unsigned int*)g,
      (__attribute__((address_space(3))) unsigned int*)l, 16, 0, 0);
}

// ---------------- fused f32 -> bf16 convert (one launch) ----------------
struct CvtSeg { const float* src; u16* dst; int nblk; };
struct CvtArgs { CvtSeg s[9]; };

__global__ __launch_bounds__(256) void cvt_all(CvtArgs a){
  int rel = blockIdx.x, seg = 0;
  while (rel >= a.s[seg].nblk){ rel -= a.s[seg].nblk; ++seg; }
  int i = rel * 256 + threadIdx.x;
  float4 v = ((const float4*)a.s[seg].src)[i];
  uint64_t p = (uint64_t)f2b(v.x) | ((uint64_t)f2b(v.y) << 16)
             | ((uint64_t)f2b(v.z) << 32) | ((uint64_t)f2b(v.w) << 48);
  *(uint64_t*)(a.s[seg].dst + (size_t)i * 4) = p;
}

// ---------------- R6-proven dual-buffer counted-vmcnt GEMM core, 128x128 ----------------
__device__ __forceinline__ void gemm_core128(const u16* __restrict__ A, const u16* __restrict__ W,
    int m0, int n0, int tid, f32x4 acc[4][4])
{
  __shared__ __align__(16) u16 As0[4096];
  __shared__ __align__(16) u16 As1[4096];
  __shared__ __align__(16) u16 Bs0[4096];
  __shared__ __align__(16) u16 Bs1[4096];

  int lane = tid & 63, w = tid >> 6;
  int wr = w >> 1, wc = w & 1;
  const int lr = lane & 15, g = lane >> 4;
  const int sslot = (g ^ ((lr >> 1) & 3)) * 8;

  int r = tid >> 2;
  int ssl = ((tid & 3) ^ ((tid >> 3) & 3)) * 8;
  const u16* Asrc = A + (size_t)(m0 + r) * 1024 + ssl;
  const u16* Bsrc = W + (size_t)(n0 + r) * 1024 + ssl;

  auto stage = [&](int k0, u16* as, u16* bs){
    async16(Asrc + k0,         as + tid*8);
    async16(Asrc + 65536 + k0, as + 2048 + tid*8);
    async16(Bsrc + k0,         bs + tid*8);
    async16(Bsrc + 65536 + k0, bs + 2048 + tid*8);
  };

  auto step = [&](u16* as, u16* bs, int kstage, bool do_stage, bool last){
    if (last) asm volatile("s_waitcnt vmcnt(0)" ::: "memory");
    else      asm volatile("s_waitcnt vmcnt(4)" ::: "memory");
    __builtin_amdgcn_sched_barrier(0);
    __builtin_amdgcn_s_barrier();
    __builtin_amdgcn_sched_barrier(0);
    short8 a[4], b[4];
    #pragma unroll
    for (int m = 0; m < 4; ++m) a[m] = *(const short8*)&as[(wr*64 + m*16 + lr)*32 + sslot];
    #pragma unroll
    for (int n = 0; n < 4; ++n) b[n] = *(const short8*)&bs[(wc*64 + n*16 + lr)*32 + sslot];
    asm volatile("s_waitcnt lgkmcnt(0)" ::: "memory");
    __builtin_amdgcn_sched_barrier(0);
    __builtin_amdgcn_s_barrier();
    __builtin_amdgcn_sched_barrier(0);
    if (do_stage) stage(kstage, as, bs);
    __builtin_amdgcn_sched_barrier(0);
    __builtin_amdgcn_s_setprio(1);
    #pragma unroll
    for (int m = 0; m < 4; ++m)
      #pragma unroll
      for (int n = 0; n < 4; ++n)
        acc[m][n] = __builtin_amdgcn_mfma_f32_16x16x32_bf16(a[m], b[n], acc[m][n], 0, 0, 0);
    __builtin_amdgcn_s_setprio(0);
  };

  stage(0,  As0, Bs0);
  stage(32, As1, Bs1);
  __builtin_amdgcn_sched_barrier(0);
  for (int it = 0; it < 16; ++it){
    step(As0, Bs0, it*64 + 64, it < 15, false);
    step(As1, Bs1, it*64 + 96, it < 15, it == 15);
  }
}

// ---------------- 64x128 variant (gemm_out, 256 blocks) ----------------
__device__ __forceinline__ void gemm_core64(const u16* __restrict__ A, const u16* __restrict__ W,
    int m0, int n0, int tid, f32x4 acc[4][2])
{
  __shared__ __align__(16) u16 As0[2048];
  __shared__ __align__(16) u16 As1[2048];
  __shared__ __align__(16) u16 Bs0[4096];
  __shared__ __align__(16) u16 Bs1[4096];

  int lane = tid & 63, wc = tid >> 6;
  const int lr = lane & 15, g = lane >> 4;
  const int sslot = (g ^ ((lr >> 1) & 3)) * 8;

  int r = tid >> 2;
  int ssl = ((tid & 3) ^ ((tid >> 3) & 3)) * 8;
  const u16* Asrc = A + (size_t)(m0 + r) * 1024 + ssl;
  const u16* Bsrc = W + (size_t)(n0 + r) * 1024 + ssl;

  auto stage = [&](int k0, u16* as, u16* bs){
    async16(Asrc + k0,         as + tid*8);
    async16(Bsrc + k0,         bs + tid*8);
    async16(Bsrc + 65536 + k0, bs + 2048 + tid*8);
  };

  auto step = [&](u16* as, u16* bs, int kstage, bool do_stage, bool last){
    if (last) asm volatile("s_waitcnt vmcnt(0)" ::: "memory");
    else      asm volatile("s_waitcnt vmcnt(3)" ::: "memory");
    __builtin_amdgcn_sched_barrier(0);
    __builtin_amdgcn_s_barrier();
    __builtin_amdgcn_sched_barrier(0);
    short8 a[4], b[2];
    #pragma unroll
    for (int m = 0; m < 4; ++m) a[m] = *(const short8*)&as[(m*16 + lr)*32 + sslot];
    #pragma unroll
    for (int n = 0; n < 2; ++n) b[n] = *(const short8*)&bs[(wc*32 + n*16 + lr)*32 + sslot];
    asm volatile("s_waitcnt lgkmcnt(0)" ::: "memory");
    __builtin_amdgcn_sched_barrier(0);
    __builtin_amdgcn_s_barrier();
    __builtin_amdgcn_sched_barrier(0);
    if (do_stage) stage(kstage, as, bs);
    __builtin_amdgcn_sched_barrier(0);
    __builtin_amdgcn_s_setprio(1);
    #pragma unroll
    for (int m = 0; m < 4; ++m)
      #pragma unroll
      for (int n = 0; n < 2; ++n)
        acc[m][n] = __builtin_amdgcn_mfma_f32_16x16x32_bf16(a[m], b[n], acc[m][n], 0, 0, 0);
    __builtin_amdgcn_s_setprio(0);
  };

  stage(0,  As0, Bs0);
  stage(32, As1, Bs1);
  __builtin_amdgcn_sched_barrier(0);
  for (int it = 0; it < 16; ++it){
    step(As0, Bs0, it*64 + 64, it < 15, false);
    step(As1, Bs1, it*64 + 96, it < 15, it == 15);
  }
}

// ---------------- fused q/k/v/pos projection GEMMs (576 blocks) ----------------
struct G4Args {
  const u16 *q, *k, *v, *p;
  const u16 *Wq, *Wk, *Wv, *Wp;
  const float *bq, *bk, *bv, *pbu, *pbv;
  u16 *qu, *qv2, *katt, *vatt, *patt;
  float *cache;
};

__global__ __launch_bounds__(256, 4) void gemm4(G4Args ga){
  int bid0 = blockIdx.x;
  int bid = (bid0 & 7) * 72 + (bid0 >> 3);   // XCD swizzle (576 = 8*72)
  int tid = threadIdx.x;
  int mode, mb; const u16 *A, *W;
  if (bid < 128)      { mode = 0; mb = bid >> 3;         A = ga.q; W = ga.Wq; }
  else if (bid < 336) { mode = 1; mb = (bid - 128) >> 3; A = ga.k; W = ga.Wk; }
  else if (bid < 544) { mode = 2; mb = (bid - 336) >> 3; A = ga.v; W = ga.Wv; }
  else                { mode = 3; mb = (bid - 544) >> 3; A = ga.p; W = ga.Wp; }
  int m0 = mb * 128, n0 = (bid & 7) * 128;
  f32x4 acc[4][4] = {};
  gemm_core128(A, W, m0, n0, tid, acc);

  int lane = tid & 63, w = tid >> 6;
  int wr = w >> 1, wc = w & 1;
  const int lr = lane & 15, g = lane >> 4;
  #pragma unroll
  for (int m = 0; m < 4; ++m){
    #pragma unroll
    for (int n = 0; n < 4; ++n){
      #pragma unroll
      for (int j = 0; j < 4; ++j){
        int row = m0 + wr*64 + m*16 + g*4 + j;
        int col = n0 + wc*64 + n*16 + lr;
        float vv = acc[m][n][j];
        if (mode == 0){
          vv += ga.bq[col];
          int h = col >> 6, d = col & 63, b_ = row >> 9, t = row & 511;
          size_t o = ((size_t)((b_*NH + h)*T1 + t))*64 + d;
          ga.qu [o] = f2b(vv + ga.pbu[col]);
          ga.qv2[o] = f2b(vv + ga.pbv[col]);
        } else if (mode == 1 || mode == 2){
          vv += (mode == 1 ? ga.bk : ga.bv)[col];
          int h = col >> 6, d = col & 63;
          int b_ = row / T2, t2 = row - b_*T2;
          size_t base = (size_t)(b_*NH + h)*T2 + t2;
          ga.cache[base*128 + (mode == 2 ? 64 : 0) + d] = vv;
          (mode == 1 ? ga.katt : ga.vatt)[base*64 + d] = f2b(vv);
        } else {
          if (row < NPLOC){
            int h = col >> 6, d = col & 63;
            ga.patt[((size_t)h*NPLOC + row)*64 + d] = f2b(vv);
          }
        }
      }
    }
  }
}

// ---------------- output GEMM (256 blocks, 64x128) ----------------
__global__ __launch_bounds__(256, 4) void gemm_out(const u16* __restrict__ A, const u16* __restrict__ W,
                                                   const float* __restrict__ bias, float* __restrict__ out){
  int bid0 = blockIdx.x;
  int bid = (bid0 & 7) * 32 + (bid0 >> 3);   // 256 = 8*32
  int m0 = (bid >> 3) * 64, n0 = (bid & 7) * 128;
  int tid = threadIdx.x;
  f32x4 acc[4][2] = {};
  gemm_core64(A, W, m0, n0, tid, acc);
  int lane = tid & 63, wc = tid >> 6;
  const int lr = lane & 15, g = lane >> 4;
  #pragma unroll
  for (int m = 0; m < 4; ++m)
    #pragma unroll
    for (int n = 0; n < 2; ++n)
      #pragma unroll
      for (int j = 0; j < 4; ++j){
        int row = m0 + m*16 + g*4 + j;
        int col = n0 + wc*32 + n*16 + lr;
        out[(size_t)row*1024 + col] = acc[m][n][j] + bias[col];
      }
}

// ---------------- attention v3: counted-vmcnt pipelined phases ----------------
// Chunks of 128 rows (16 KB), ping-pong S0/S1. P: 4 chunks (rows 448..511 are
// garbage but provably discarded: jj = nl+r-63 >= 385 > 383). K: 3 chunks.
// V: reg-staged (T14), transposed into the free S-buffer during SM/PV.
#define PHASE_HEAD(N) \
  asm volatile("s_waitcnt vmcnt(" #N ")" ::: "memory"); \
  __builtin_amdgcn_sched_barrier(0); \
  __builtin_amdgcn_s_barrier(); \
  __builtin_amdgcn_sched_barrier(0);

#define PHASE_TAIL \
  __builtin_amdgcn_sched_barrier(0); \
  __builtin_amdgcn_s_barrier(); \
  __builtin_amdgcn_sched_barrier(0);

#define VT_TAIL \
  asm volatile("s_waitcnt lgkmcnt(0)" ::: "memory"); \
  __builtin_amdgcn_sched_barrier(0); \
  __builtin_amdgcn_s_barrier(); \
  __builtin_amdgcn_sched_barrier(0);

__global__ __launch_bounds__(256, 2) void attn_v3(
    const u16* __restrict__ qu, const u16* __restrict__ qv,
    const u16* __restrict__ katt, const u16* __restrict__ vatt,
    const u16* __restrict__ patt, u16* __restrict__ xout)
{
  __shared__ __align__(16) u16 SB[64*384];   // 49152 B (bd scores -> P)
  __shared__ __align__(16) u16 S0[8192];     // 16384 B staging ping
  __shared__ __align__(16) u16 S1[8192];     // 16384 B staging pong

  int tid = threadIdx.x, lane = tid & 63, w = tid >> 6;
  int bid0 = blockIdx.x;
  int bid = (bid0 & 7) * 64 + (bid0 >> 3);   // XCD swizzle
  int c = bid & 7, h = (bid >> 3) & 15, b = bid >> 7;
  int bh = b*NH + h;
  const int lr = lane & 15, g = lane >> 4, lk = g * 8;

  auto sb_off = [&](int r, int cc) -> uint32_t {
    return ((uint32_t)(r*384 + cc)*2) ^ ((uint32_t)(r & 15) << 4);
  };
  auto stg_swz = [&](uint32_t o) -> uint32_t { return o ^ (((o >> 7) & 7u) << 4); };
  auto vt_off = [&](int d, int kk) -> uint32_t {
    return ((uint32_t)(d*128 + kk)*2) ^ ((uint32_t)(((d & 7) ^ ((d >> 3) & 7))) << 4);
  };

  // Q fragments straight to registers
  int qrow = 16*w + lr;
  const u16* qub = qu + ((size_t)bh*T1 + c*64 + qrow)*64;
  const u16* qvb = qv + ((size_t)bh*T1 + c*64 + qrow)*64;
  short8 qu0 = *(const short8*)(qub + lk);
  short8 qu1 = *(const short8*)(qub + 32 + lk);
  short8 qv0 = *(const short8*)(qvb + lk);
  short8 qv1 = *(const short8*)(qvb + 32 + lk);
  __builtin_amdgcn_sched_barrier(0);

  const char* psrc = (const char*)(patt + (size_t)h*NPLOC*64);
  const char* ksrc = (const char*)(katt + ((size_t)bh*T2 + c*64)*64);
  const u16*  vsrc = vatt + ((size_t)bh*T2 + c*64)*64;

  auto issue4 = [&](const char* src, u16* dst){
    #pragma unroll
    for (int i = 0; i < 4; ++i){
      uint32_t o = (uint32_t)(i*256 + tid)*16;
      async16(src + stg_swz(o), (char*)dst + o);
    }
  };

  uint4 vstg0, vstg1, vstg2, vstg3;
  auto vload = [&](int vc){
    const u16* vb = vsrc + vc*8192;
    vstg0 = *(const uint4*)(vb + (0*256 + tid)*8);
    vstg1 = *(const uint4*)(vb + (1*256 + tid)*8);
    vstg2 = *(const uint4*)(vb + (2*256 + tid)*8);
    vstg3 = *(const uint4*)(vb + (3*256 + tid)*8);
  };
  auto vtwrite = [&](u16* sbuf){
    #pragma unroll
    for (int i = 0; i < 4; ++i){
      uint4 vv4 = (i == 0) ? vstg0 : (i == 1) ? vstg1 : (i == 2) ? vstg2 : vstg3;
      int e = (i*256 + tid)*8;
      int kk = e >> 6, d0 = e & 63;
      u16 uu[8] = { (u16)(vv4.x & 0xffff), (u16)(vv4.x >> 16), (u16)(vv4.y & 0xffff), (u16)(vv4.y >> 16),
                    (u16)(vv4.z & 0xffff), (u16)(vv4.z >> 16), (u16)(vv4.w & 0xffff), (u16)(vv4.w >> 16) };
      #pragma unroll
      for (int j = 0; j < 8; ++j)
        *(u16*)((char*)sbuf + vt_off(d0 + j, kk)) = uu[j];
    }
  };

  #define BD_CHUNK(PC, SBUF) \
    _Pragma("unroll") \
    for (int nt = 0; nt < 8; ++nt){ \
      uint32_t bo = (uint32_t)((nt*16 + lr)*64)*2; \
      short8 b0 = *(const short8*)((const char*)SBUF + stg_swz(bo + lk*2)); \
      short8 b1 = *(const short8*)((const char*)SBUF + stg_swz(bo + (32 + lk)*2)); \
      f32x4 acc = {0.f,0.f,0.f,0.f}; \
      __builtin_amdgcn_s_setprio(1); \
      acc = __builtin_amdgcn_mfma_f32_16x16x32_bf16(qv0, b0, acc, 0, 0, 0); \
      acc = __builtin_amdgcn_mfma_f32_16x16x32_bf16(qv1, b1, acc, 0, 0, 0); \
      __builtin_amdgcn_s_setprio(0); \
      int nl = (PC)*128 + nt*16 + lr; \
      _Pragma("unroll") \
      for (int j = 0; j < 4; ++j){ \
        int r = 16*w + g*4 + j; \
        int jj = nl + r - 63; \
        if (jj >= 0 && jj < 384) *(u16*)((char*)SB + sb_off(r, jj)) = f2b(acc[j]); \
      } \
    }

  #define AC_CHUNK(KC, SBUF) \
    _Pragma("unroll") \
    for (int nt = 0; nt < 8; ++nt){ \
      uint32_t bo = (uint32_t)((nt*16 + lr)*64)*2; \
      short8 b0 = *(const short8*)((const char*)SBUF + stg_swz(bo + lk*2)); \
      short8 b1 = *(const short8*)((const char*)SBUF + stg_swz(bo + (32 + lk)*2)); \
      __builtin_amdgcn_s_setprio(1); \
      accs[(KC)*8 + nt] = __builtin_amdgcn_mfma_f32_16x16x32_bf16(qu0, b0, accs[(KC)*8 + nt], 0, 0, 0); \
      accs[(KC)*8 + nt] = __builtin_amdgcn_mfma_f32_16x16x32_bf16(qu1, b1, accs[(KC)*8 + nt], 0, 0, 0); \
      __builtin_amdgcn_s_setprio(0); \
    }

  #define PV_CHUNK(VC, SBUF) \
    _Pragma("unroll") \
    for (int kt = 0; kt < 4; ++kt){ \
      short8 a = *(const short8*)((const char*)SB + sb_off(16*w + lr, (VC)*128 + kt*32 + lk)); \
      __builtin_amdgcn_s_setprio(1); \
      _Pragma("unroll") \
      for (int n = 0; n < 4; ++n){ \
        short8 bb = *(const short8*)((const char*)SBUF + vt_off(n*16 + lr, kt*32 + lk)); \
        acco[n] = __builtin_amdgcn_mfma_f32_16x16x32_bf16(a, bb, acco[n], 0, 0, 0); \
      } \
      __builtin_amdgcn_s_setprio(0); \
    }

  f32x4 accs[24];
  #pragma unroll
  for (int t = 0; t < 24; ++t) accs[t] = (f32x4){0.f,0.f,0.f,0.f};
  f32x4 acco[4] = {};

  issue4(psrc,          S0);
  issue4(psrc + 16384,  S1);

  PHASE_HEAD(4) BD_CHUNK(0, S0) PHASE_TAIL issue4(psrc + 32768, S0);
  PHASE_HEAD(4) BD_CHUNK(1, S1) PHASE_TAIL issue4(psrc + 49152, S1);
  PHASE_HEAD(4) BD_CHUNK(2, S0) PHASE_TAIL issue4(ksrc,         S0);
  PHASE_HEAD(4) BD_CHUNK(3, S1) PHASE_TAIL issue4(ksrc + 16384, S1);
  PHASE_HEAD(4) AC_CHUNK(0, S0) PHASE_TAIL issue4(ksrc + 32768, S0);
  PHASE_HEAD(4) AC_CHUNK(1, S1) PHASE_TAIL vload(0);
  PHASE_HEAD(4) AC_CHUNK(2, S0)

  // ---- softmax in registers (bd add from SB own-wave rows; P back to SB) ----
  #pragma unroll
  for (int t = 0; t < 24; ++t)
    #pragma unroll
    for (int j = 0; j < 4; ++j){
      int r = 16*w + g*4 + j, cc = t*16 + lr;
      accs[t][j] += b2f(*(const u16*)((const char*)SB + sb_off(r, cc)));
    }
  float mx[4] = {-1e30f,-1e30f,-1e30f,-1e30f};
  #pragma unroll
  for (int t = 0; t < 24; ++t)
    #pragma unroll
    for (int j = 0; j < 4; ++j) mx[j] = fmaxf(mx[j], accs[t][j]);
  #pragma unroll
  for (int j = 0; j < 4; ++j){
    mx[j] = fmaxf(mx[j], __shfl_xor(mx[j], 1));
    mx[j] = fmaxf(mx[j], __shfl_xor(mx[j], 2));
    mx[j] = fmaxf(mx[j], __shfl_xor(mx[j], 4));
    mx[j] = fmaxf(mx[j], __shfl_xor(mx[j], 8));
  }
  float sm[4] = {0.f,0.f,0.f,0.f};
  #pragma unroll
  for (int t = 0; t < 24; ++t)
    #pragma unroll
    for (int j = 0; j < 4; ++j){
      accs[t][j] = __expf((accs[t][j] - mx[j]) * 0.125f);
      sm[j] += accs[t][j];
    }
  #pragma unroll
  for (int j = 0; j < 4; ++j){
    sm[j] += __shfl_xor(sm[j], 1);
    sm[j] += __shfl_xor(sm[j], 2);
    sm[j] += __shfl_xor(sm[j], 4);
    sm[j] += __shfl_xor(sm[j], 8);
    sm[j] = 1.f / sm[j];
  }
  #pragma unroll
  for (int t = 0; t < 24; ++t)
    #pragma unroll
    for (int j = 0; j < 4; ++j){
      int r = 16*w + g*4 + j, cc = t*16 + lr;
      *(u16*)((char*)SB + sb_off(r, cc)) = f2b(accs[t][j] * sm[j]);
    }

  // V0 -> Vt in S1 (S1's readers sealed by AC2's leading barrier); prefetch V1
  asm volatile("s_waitcnt vmcnt(0)" ::: "memory");
  __builtin_amdgcn_sched_barrier(0);
  vtwrite(S1);
  vload(1);
  VT_TAIL                      // bar1: SM + Vt0 visible

  PV_CHUNK(0, S1)
  asm volatile("s_waitcnt vmcnt(0)" ::: "memory");
  __builtin_amdgcn_sched_barrier(0);
  vtwrite(S0);                 // S0's readers (AC2) sealed by bar1
  vload(2);
  VT_TAIL                      // bar2: PV0 reads done, Vt1 visible

  PV_CHUNK(1, S0)
  asm volatile("s_waitcnt vmcnt(0)" ::: "memory");
  __builtin_amdgcn_sched_barrier(0);
  vtwrite(S1);                 // S1's readers (PV0) sealed by bar2
  VT_TAIL                      // bar3

  PV_CHUNK(2, S1)

  #pragma unroll
  for (int n = 0; n < 4; ++n)
    #pragma unroll
    for (int j = 0; j < 4; ++j){
      int r = 16*w + g*4 + j;
      int t = c*64 + r, d = n*16 + lr;
      xout[((size_t)b*T1 + t)*1024 + h*64 + d] = f2b(acco[n][j]);
    }
}

// ---------------- launch ----------------
extern "C" void kernel_launch(void* const* d_in, const int* in_sizes, int n_in,
                              void* d_out, int out_size, void* d_ws, size_t ws_size,
                              hipStream_t stream)
{
  const float* query = (const float*)d_in[0];
  const float* key   = (const float*)d_in[1];
  const float* value = (const float*)d_in[2];
  const float* pos   = (const float*)d_in[3];
  const float* Wq  = (const float*)d_in[4];
  const float* bq  = (const float*)d_in[5];
  const float* Wk  = (const float*)d_in[6];
  const float* bk  = (const float*)d_in[7];
  const float* Wv  = (const float*)d_in[8];
  const float* bv  = (const float*)d_in[9];
  const float* Wp  = (const float*)d_in[10];
  const float* Wo  = (const float*)d_in[11];
  const float* bo  = (const float*)d_in[12];
  const float* pbu = (const float*)d_in[13];
  const float* pbv = (const float*)d_in[14];

  float* out   = (float*)d_out;
  float* cache = out + 2097152;

  u16* ws     = (u16*)d_ws;
  u16* q_bf   = ws;
  u16* key_bf = ws + 2097152;
  u16* val_bf = ws + 5505024;
  u16* pos_bf = ws + 8912896;
  u16* Wq_bf  = ws + 9437184;
  u16* Wk_bf  = ws + 10485760;
  u16* Wv_bf  = ws + 11534336;
  u16* Wp_bf  = ws + 12582912;
  u16* Wo_bf  = ws + 13631488;
  u16* qu_bf  = ws + 14680064;
  u16* qv_bf  = ws + 16777216;
  u16* katt   = ws + 18874368;
  u16* vatt   = ws + 22282240;
  u16* patt   = ws + 25690112;
  u16* x_bf   = ws + 26148864;

  CvtArgs ca;
  ca.s[0] = { query,            q_bf,   2048 };
  ca.s[1] = { key,              key_bf, 3328 };
  ca.s[2] = { value,            val_bf, 3328 };
  ca.s[3] = { Wq,               Wq_bf,  1024 };
  ca.s[4] = { Wk,               Wk_bf,  1024 };
  ca.s[5] = { Wv,               Wv_bf,  1024 };
  ca.s[6] = { Wp,               Wp_bf,  1024 };
  ca.s[7] = { Wo,               Wo_bf,  1024 };
  ca.s[8] = { pos + 448*1024,   pos_bf, 448 };
  cvt_all<<<14272, 256, 0, stream>>>(ca);

  G4Args ga;
  ga.q = q_bf; ga.k = key_bf; ga.v = val_bf; ga.p = pos_bf;
  ga.Wq = Wq_bf; ga.Wk = Wk_bf; ga.Wv = Wv_bf; ga.Wp = Wp_bf;
  ga.bq = bq; ga.bk = bk; ga.bv = bv; ga.pbu = pbu; ga.pbv = pbv;
  ga.qu = qu_bf; ga.qv2 = qv_bf; ga.katt = katt; ga.vatt = vatt; ga.patt = patt;
  ga.cache = cache;
  gemm4<<<576, 256, 0, stream>>>(ga);

  attn_v3<<<512, 256, 0, stream>>>(qu_bf, qv_bf, katt, vatt, patt, x_bf);

  gemm_out<<<256, 256, 0, stream>>>(x_bf, Wo_bf, bo, out);
}

// Round 9
// 89.505 us; speedup vs baseline: 1.0340x; 1.0038x over previous
//
#include <hip/hip_runtime.h>
#include <cstdint>

typedef unsigned short u16;
using short8 = __attribute__((ext_vector_type(8))) short;
using f32x4  = __attribute__((ext_vector_type(4))) float;

#define T1 512
#define T2 832
#define NH 16
#define NPLOC 448

__device__ __forceinline__ u16 f2b(float f){
  union { float f; uint32_t u; } c; c.f = f;
  uint32_t u = c.u;
  u += 0x7fffu + ((u >> 16) & 1u);   // RNE bf16
  return (u16)(u >> 16);
}
__device__ __forceinline__ float b2f(u16 b){
  union { uint32_t u; float f; } c; c.u = (uint32_t)b << 16; return c.f;
}
__device__ __forceinline__ void async16(const void* g, void* l){
  __builtin_amdgcn_global_load_lds(
      (const __attribute__((address_space(1))) unsigned int*)g,
      (__attribute__((address_space(3))) unsigned int*)l, 16, 0, 0);
}

#define SB0 __builtin_amdgcn_sched_barrier(0)

// ---------------- weights-only f32 -> bf16 convert ----------------
struct CvtSeg { const float* src; u16* dst; int nblk; };
struct CvtArgs { CvtSeg s[5]; };

__global__ __launch_bounds__(256) void cvt_all(CvtArgs a){
  int rel = blockIdx.x, seg = 0;
  while (rel >= a.s[seg].nblk){ rel -= a.s[seg].nblk; ++seg; }
  int i = rel * 256 + threadIdx.x;
  float4 v = ((const float4*)a.s[seg].src)[i];
  uint64_t p = (uint64_t)f2b(v.x) | ((uint64_t)f2b(v.y) << 16)
             | ((uint64_t)f2b(v.z) << 32) | ((uint64_t)f2b(v.w) << 48);
  *(uint64_t*)(a.s[seg].dst + (size_t)i * 4) = p;
}

// ---------------- gemm4 core: f32-A reg-staged convert, bf16-B DMA ----------------
// 128x128 tile, BK=32, dual LDS buffer. Per step t:
//   vmcnt(6)[B(t) done] -> barrier -> ds_read(t) -> lgkm(0) -> barrier(readers done)
//   -> vmcnt(2)[A(t+2) regs ready] -> ds_write A(t+2) -> issue A(t+3) f32 loads
//   -> issue B(t+2) DMA -> MFMA(t).
// Issue order per stage point is [A x4, B x2]; vmcnt retires in order.
struct G4Args {
  const float *q, *k, *v, *p;
  const u16 *Wq, *Wk, *Wv, *Wp;
  const float *bq, *bk, *bv, *pbu, *pbv;
  u16 *qu, *qv2, *katt, *vatt, *patt;
  float *cache;
};

__global__ __launch_bounds__(256, 3) void gemm4(G4Args ga){
  __shared__ __align__(16) u16 As0[4096];
  __shared__ __align__(16) u16 As1[4096];
  __shared__ __align__(16) u16 Bs0[4096];
  __shared__ __align__(16) u16 Bs1[4096];

  int bid0 = blockIdx.x;
  int bid = (bid0 & 7) * 72 + (bid0 >> 3);   // XCD swizzle (576 = 8*72)
  int tid = threadIdx.x;
  int mode, mb; const float *A; const u16 *W;
  if (bid < 128)      { mode = 0; mb = bid >> 3;         A = ga.q; W = ga.Wq; }
  else if (bid < 336) { mode = 1; mb = (bid - 128) >> 3; A = ga.k; W = ga.Wk; }
  else if (bid < 544) { mode = 2; mb = (bid - 336) >> 3; A = ga.v; W = ga.Wv; }
  else                { mode = 3; mb = (bid - 544) >> 3; A = ga.p; W = ga.Wp; }
  int m0 = mb * 128, n0 = (bid & 7) * 128;

  int lane = tid & 63, w = tid >> 6;
  int wr = w >> 1, wc = w & 1;
  const int lr = lane & 15, g = lane >> 4;
  const int sslot = (g ^ ((lr >> 1) & 3)) * 8;

  int r = tid >> 2;
  int ssl = ((tid & 3) ^ ((tid >> 3) & 3)) * 8;
  const float* Af  = A + (size_t)(m0 + r) * 1024 + ssl;
  const u16*  Bsrc = W + (size_t)(n0 + r) * 1024 + ssl;

  f32x4 acc[4][4] = {};
  float4 xA0, xA1, xA2, xA3, yA0, yA1, yA2, yA3;

#define LOADX(K) { xA0 = *(const float4*)(Af+(K)); xA1 = *(const float4*)(Af+(K)+4); \
                   xA2 = *(const float4*)(Af+(K)+65536); xA3 = *(const float4*)(Af+(K)+65536+4); }
#define LOADY(K) { yA0 = *(const float4*)(Af+(K)); yA1 = *(const float4*)(Af+(K)+4); \
                   yA2 = *(const float4*)(Af+(K)+65536); yA3 = *(const float4*)(Af+(K)+65536+4); }
#define WRX(AS) { short8 p0, p1; \
  p0[0]=(short)f2b(xA0.x); p0[1]=(short)f2b(xA0.y); p0[2]=(short)f2b(xA0.z); p0[3]=(short)f2b(xA0.w); \
  p0[4]=(short)f2b(xA1.x); p0[5]=(short)f2b(xA1.y); p0[6]=(short)f2b(xA1.z); p0[7]=(short)f2b(xA1.w); \
  p1[0]=(short)f2b(xA2.x); p1[1]=(short)f2b(xA2.y); p1[2]=(short)f2b(xA2.z); p1[3]=(short)f2b(xA2.w); \
  p1[4]=(short)f2b(xA3.x); p1[5]=(short)f2b(xA3.y); p1[6]=(short)f2b(xA3.z); p1[7]=(short)f2b(xA3.w); \
  *(short8*)((AS) + tid*8) = p0; *(short8*)((AS) + 2048 + tid*8) = p1; }
#define WRY(AS) { short8 p0, p1; \
  p0[0]=(short)f2b(yA0.x); p0[1]=(short)f2b(yA0.y); p0[2]=(short)f2b(yA0.z); p0[3]=(short)f2b(yA0.w); \
  p0[4]=(short)f2b(yA1.x); p0[5]=(short)f2b(yA1.y); p0[6]=(short)f2b(yA1.z); p0[7]=(short)f2b(yA1.w); \
  p1[0]=(short)f2b(yA2.x); p1[1]=(short)f2b(yA2.y); p1[2]=(short)f2b(yA2.z); p1[3]=(short)f2b(yA2.w); \
  p1[4]=(short)f2b(yA3.x); p1[5]=(short)f2b(yA3.y); p1[6]=(short)f2b(yA3.z); p1[7]=(short)f2b(yA3.w); \
  *(short8*)((AS) + tid*8) = p0; *(short8*)((AS) + 2048 + tid*8) = p1; }
#define ISSUEB(BS, K) { async16(Bsrc + (K), (BS) + tid*8); \
                        async16(Bsrc + 65536 + (K), (BS) + 2048 + tid*8); }

#define GSTEP(AS, BS, TOPW, DW, WRM, LDM, KA, KB, IA, IB) { \
  asm volatile("s_waitcnt vmcnt(" #TOPW ")" ::: "memory"); \
  SB0; __builtin_amdgcn_s_barrier(); SB0; \
  short8 a_[4], b_[4]; \
  _Pragma("unroll") \
  for (int m = 0; m < 4; ++m) a_[m] = *(const short8*)&(AS)[(wr*64 + m*16 + lr)*32 + sslot]; \
  _Pragma("unroll") \
  for (int n = 0; n < 4; ++n) b_[n] = *(const short8*)&(BS)[(wc*64 + n*16 + lr)*32 + sslot]; \
  asm volatile("s_waitcnt lgkmcnt(0)" ::: "memory"); \
  SB0; __builtin_amdgcn_s_barrier(); SB0; \
  if (DW){ asm volatile("s_waitcnt vmcnt(2)" ::: "memory"); SB0; WRM(AS); } \
  if (IA){ LDM(KA); } \
  if (IB){ ISSUEB(BS, KB); } \
  SB0; \
  __builtin_amdgcn_s_setprio(1); \
  _Pragma("unroll") \
  for (int m = 0; m < 4; ++m) \
    _Pragma("unroll") \
    for (int n = 0; n < 4; ++n) \
      acc[m][n] = __builtin_amdgcn_mfma_f32_16x16x32_bf16(a_[m], b_[n], acc[m][n], 0, 0, 0); \
  __builtin_amdgcn_s_setprio(0); }

  // prologue: A0->x, B0, A1->y | wait A0 | write A0 | A2->x, B1 | wait A1 | write A1
  LOADX(0);
  ISSUEB(Bs0, 0);
  LOADY(32);
  asm volatile("s_waitcnt vmcnt(6)" ::: "memory"); SB0;
  WRX(As0);
  LOADX(64);
  ISSUEB(Bs1, 32);
  asm volatile("s_waitcnt vmcnt(6)" ::: "memory"); SB0;
  WRY(As1);
  asm volatile("s_waitcnt lgkmcnt(0)" ::: "memory"); SB0;

  for (int it = 0; it < 15; ++it){
    int t0 = 2*it;
    GSTEP(As0, Bs0, 6, 1, WRX, LOADY, (t0+3)*32, (t0+2)*32, 1, 1)        // t even
    GSTEP(As1, Bs1, 6, 1, WRY, LOADX, (t0+4)*32, (t0+3)*32, it < 14, 1)  // t odd
  }
  GSTEP(As0, Bs0, 2, 0, WRX, LOADX, 0, 0, 0, 0)   // t = 30
  GSTEP(As1, Bs1, 0, 0, WRX, LOADX, 0, 0, 0, 0)   // t = 31

  // ---- epilogue ----
  #pragma unroll
  for (int m = 0; m < 4; ++m){
    #pragma unroll
    for (int n = 0; n < 4; ++n){
      #pragma unroll
      for (int j = 0; j < 4; ++j){
        int row = m0 + wr*64 + m*16 + g*4 + j;
        int col = n0 + wc*64 + n*16 + lr;
        float vv = acc[m][n][j];
        if (mode == 0){
          vv += ga.bq[col];
          int h = col >> 6, d = col & 63, b_ = row >> 9, t = row & 511;
          size_t o = ((size_t)((b_*NH + h)*T1 + t))*64 + d;
          ga.qu [o] = f2b(vv + ga.pbu[col]);
          ga.qv2[o] = f2b(vv + ga.pbv[col]);
        } else if (mode == 1 || mode == 2){
          vv += (mode == 1 ? ga.bk : ga.bv)[col];
          int h = col >> 6, d = col & 63;
          int b_ = row / T2, t2 = row - b_*T2;
          size_t base = (size_t)(b_*NH + h)*T2 + t2;
          ga.cache[base*128 + (mode == 2 ? 64 : 0) + d] = vv;
          (mode == 1 ? ga.katt : ga.vatt)[base*64 + d] = f2b(vv);
        } else {
          if (row < NPLOC){
            int h = col >> 6, d = col & 63;
            ga.patt[((size_t)h*NPLOC + row)*64 + d] = f2b(vv);
          }
        }
      }
    }
  }
}

// ---------------- 64x128 bf16 DMA core (gemm_out, 256 blocks) ----------------
__device__ __forceinline__ void gemm_core64(const u16* __restrict__ A, const u16* __restrict__ W,
    int m0, int n0, int tid, f32x4 acc[4][2])
{
  __shared__ __align__(16) u16 As0[2048];
  __shared__ __align__(16) u16 As1[2048];
  __shared__ __align__(16) u16 Bs0[4096];
  __shared__ __align__(16) u16 Bs1[4096];

  int lane = tid & 63, wc = tid >> 6;
  const int lr = lane & 15, g = lane >> 4;
  const int sslot = (g ^ ((lr >> 1) & 3)) * 8;

  int r = tid >> 2;
  int ssl = ((tid & 3) ^ ((tid >> 3) & 3)) * 8;
  const u16* Asrc = A + (size_t)(m0 + r) * 1024 + ssl;
  const u16* Bsrc = W + (size_t)(n0 + r) * 1024 + ssl;

  auto stage = [&](int k0, u16* as, u16* bs){
    async16(Asrc + k0,         as + tid*8);
    async16(Bsrc + k0,         bs + tid*8);
    async16(Bsrc + 65536 + k0, bs + 2048 + tid*8);
  };

  auto step = [&](u16* as, u16* bs, int kstage, bool do_stage, bool last){
    if (last) asm volatile("s_waitcnt vmcnt(0)" ::: "memory");
    else      asm volatile("s_waitcnt vmcnt(3)" ::: "memory");
    SB0; __builtin_amdgcn_s_barrier(); SB0;
    short8 a[4], b[2];
    #pragma unroll
    for (int m = 0; m < 4; ++m) a[m] = *(const short8*)&as[(m*16 + lr)*32 + sslot];
    #pragma unroll
    for (int n = 0; n < 2; ++n) b[n] = *(const short8*)&bs[(wc*32 + n*16 + lr)*32 + sslot];
    asm volatile("s_waitcnt lgkmcnt(0)" ::: "memory");
    SB0; __builtin_amdgcn_s_barrier(); SB0;
    if (do_stage) stage(kstage, as, bs);
    SB0;
    __builtin_amdgcn_s_setprio(1);
    #pragma unroll
    for (int m = 0; m < 4; ++m)
      #pragma unroll
      for (int n = 0; n < 2; ++n)
        acc[m][n] = __builtin_amdgcn_mfma_f32_16x16x32_bf16(a[m], b[n], acc[m][n], 0, 0, 0);
    __builtin_amdgcn_s_setprio(0);
  };

  stage(0,  As0, Bs0);
  stage(32, As1, Bs1);
  SB0;
  for (int it = 0; it < 16; ++it){
    step(As0, Bs0, it*64 + 64, it < 15, false);
    step(As1, Bs1, it*64 + 96, it < 15, it == 15);
  }
}

__global__ __launch_bounds__(256, 4) void gemm_out(const u16* __restrict__ A, const u16* __restrict__ W,
                                                   const float* __restrict__ bias, float* __restrict__ out){
  int bid0 = blockIdx.x;
  int bid = (bid0 & 7) * 32 + (bid0 >> 3);   // 256 = 8*32
  int m0 = (bid >> 3) * 64, n0 = (bid & 7) * 128;
  int tid = threadIdx.x;
  f32x4 acc[4][2] = {};
  gemm_core64(A, W, m0, n0, tid, acc);
  int lane = tid & 63, wc = tid >> 6;
  const int lr = lane & 15, g = lane >> 4;
  #pragma unroll
  for (int m = 0; m < 4; ++m)
    #pragma unroll
    for (int n = 0; n < 2; ++n)
      #pragma unroll
      for (int j = 0; j < 4; ++j){
        int row = m0 + m*16 + g*4 + j;
        int col = n0 + wc*32 + n*16 + lr;
        out[(size_t)row*1024 + col] = acc[m][n][j] + bias[col];
      }
}

// ---------------- attention v3 (R8-proven) ----------------
#define PHASE_HEAD(N) \
  asm volatile("s_waitcnt vmcnt(" #N ")" ::: "memory"); \
  SB0; __builtin_amdgcn_s_barrier(); SB0;

#define PHASE_TAIL \
  SB0; __builtin_amdgcn_s_barrier(); SB0;

#define VT_TAIL \
  asm volatile("s_waitcnt lgkmcnt(0)" ::: "memory"); \
  SB0; __builtin_amdgcn_s_barrier(); SB0;

__global__ __launch_bounds__(256, 2) void attn_v3(
    const u16* __restrict__ qu, const u16* __restrict__ qv,
    const u16* __restrict__ katt, const u16* __restrict__ vatt,
    const u16* __restrict__ patt, u16* __restrict__ xout)
{
  __shared__ __align__(16) u16 SB[64*384];   // 49152 B (bd scores -> P)
  __shared__ __align__(16) u16 S0[8192];     // 16384 B staging ping
  __shared__ __align__(16) u16 S1[8192];     // 16384 B staging pong

  int tid = threadIdx.x, lane = tid & 63, w = tid >> 6;
  int bid0 = blockIdx.x;
  int bid = (bid0 & 7) * 64 + (bid0 >> 3);   // XCD swizzle
  int c = bid & 7, h = (bid >> 3) & 15, b = bid >> 7;
  int bh = b*NH + h;
  const int lr = lane & 15, g = lane >> 4, lk = g * 8;

  auto sb_off = [&](int r, int cc) -> uint32_t {
    return ((uint32_t)(r*384 + cc)*2) ^ ((uint32_t)(r & 15) << 4);
  };
  auto stg_swz = [&](uint32_t o) -> uint32_t { return o ^ (((o >> 7) & 7u) << 4); };
  auto vt_off = [&](int d, int kk) -> uint32_t {
    return ((uint32_t)(d*128 + kk)*2) ^ ((uint32_t)(((d & 7) ^ ((d >> 3) & 7))) << 4);
  };

  int qrow = 16*w + lr;
  const u16* qub = qu + ((size_t)bh*T1 + c*64 + qrow)*64;
  const u16* qvb = qv + ((size_t)bh*T1 + c*64 + qrow)*64;
  short8 qu0 = *(const short8*)(qub + lk);
  short8 qu1 = *(const short8*)(qub + 32 + lk);
  short8 qv0 = *(const short8*)(qvb + lk);
  short8 qv1 = *(const short8*)(qvb + 32 + lk);
  SB0;

  const char* psrc = (const char*)(patt + (size_t)h*NPLOC*64);
  const char* ksrc = (const char*)(katt + ((size_t)bh*T2 + c*64)*64);
  const u16*  vsrc = vatt + ((size_t)bh*T2 + c*64)*64;

  auto issue4 = [&](const char* src, u16* dst){
    #pragma unroll
    for (int i = 0; i < 4; ++i){
      uint32_t o = (uint32_t)(i*256 + tid)*16;
      async16(src + stg_swz(o), (char*)dst + o);
    }
  };

  uint4 vstg0, vstg1, vstg2, vstg3;
  auto vload = [&](int vc){
    const u16* vb = vsrc + vc*8192;
    vstg0 = *(const uint4*)(vb + (0*256 + tid)*8);
    vstg1 = *(const uint4*)(vb + (1*256 + tid)*8);
    vstg2 = *(const uint4*)(vb + (2*256 + tid)*8);
    vstg3 = *(const uint4*)(vb + (3*256 + tid)*8);
  };
  auto vtwrite = [&](u16* sbuf){
    #pragma unroll
    for (int i = 0; i < 4; ++i){
      uint4 vv4 = (i == 0) ? vstg0 : (i == 1) ? vstg1 : (i == 2) ? vstg2 : vstg3;
      int e = (i*256 + tid)*8;
      int kk = e >> 6, d0 = e & 63;
      u16 uu[8] = { (u16)(vv4.x & 0xffff), (u16)(vv4.x >> 16), (u16)(vv4.y & 0xffff), (u16)(vv4.y >> 16),
                    (u16)(vv4.z & 0xffff), (u16)(vv4.z >> 16), (u16)(vv4.w & 0xffff), (u16)(vv4.w >> 16) };
      #pragma unroll
      for (int j = 0; j < 8; ++j)
        *(u16*)((char*)sbuf + vt_off(d0 + j, kk)) = uu[j];
    }
  };

  #define BD_CHUNK(PC, SBUF) \
    _Pragma("unroll") \
    for (int nt = 0; nt < 8; ++nt){ \
      uint32_t bo = (uint32_t)((nt*16 + lr)*64)*2; \
      short8 b0 = *(const short8*)((const char*)SBUF + stg_swz(bo + lk*2)); \
      short8 b1 = *(const short8*)((const char*)SBUF + stg_swz(bo + (32 + lk)*2)); \
      f32x4 acc = {0.f,0.f,0.f,0.f}; \
      __builtin_amdgcn_s_setprio(1); \
      acc = __builtin_amdgcn_mfma_f32_16x16x32_bf16(qv0, b0, acc, 0, 0, 0); \
      acc = __builtin_amdgcn_mfma_f32_16x16x32_bf16(qv1, b1, acc, 0, 0, 0); \
      __builtin_amdgcn_s_setprio(0); \
      int nl = (PC)*128 + nt*16 + lr; \
      _Pragma("unroll") \
      for (int j = 0; j < 4; ++j){ \
        int r = 16*w + g*4 + j; \
        int jj = nl + r - 63; \
        if (jj >= 0 && jj < 384) *(u16*)((char*)SB + sb_off(r, jj)) = f2b(acc[j]); \
      } \
    }

  #define AC_CHUNK(KC, SBUF) \
    _Pragma("unroll") \
    for (int nt = 0; nt < 8; ++nt){ \
      uint32_t bo = (uint32_t)((nt*16 + lr)*64)*2; \
      short8 b0 = *(const short8*)((const char*)SBUF + stg_swz(bo + lk*2)); \
      short8 b1 = *(const short8*)((const char*)SBUF + stg_swz(bo + (32 + lk)*2)); \
      __builtin_amdgcn_s_setprio(1); \
      accs[(KC)*8 + nt] = __builtin_amdgcn_mfma_f32_16x16x32_bf16(qu0, b0, accs[(KC)*8 + nt], 0, 0, 0); \
      accs[(KC)*8 + nt] = __builtin_amdgcn_mfma_f32_16x16x32_bf16(qu1, b1, accs[(KC)*8 + nt], 0, 0, 0); \
      __builtin_amdgcn_s_setprio(0); \
    }

  #define PV_CHUNK(VC, SBUF) \
    _Pragma("unroll") \
    for (int kt = 0; kt < 4; ++kt){ \
      short8 a = *(const short8*)((const char*)SB + sb_off(16*w + lr, (VC)*128 + kt*32 + lk)); \
      __builtin_amdgcn_s_setprio(1); \
      _Pragma("unroll") \
      for (int n = 0; n < 4; ++n){ \
        short8 bb = *(const short8*)((const char*)SBUF + vt_off(n*16 + lr, kt*32 + lk)); \
        acco[n] = __builtin_amdgcn_mfma_f32_16x16x32_bf16(a, bb, acco[n], 0, 0, 0); \
      } \
      __builtin_amdgcn_s_setprio(0); \
    }

  f32x4 accs[24];
  #pragma unroll
  for (int t = 0; t < 24; ++t) accs[t] = (f32x4){0.f,0.f,0.f,0.f};
  f32x4 acco[4] = {};

  issue4(psrc,          S0);
  issue4(psrc + 16384,  S1);

  PHASE_HEAD(4) BD_CHUNK(0, S0) PHASE_TAIL issue4(psrc + 32768, S0);
  PHASE_HEAD(4) BD_CHUNK(1, S1) PHASE_TAIL issue4(psrc + 49152, S1);
  PHASE_HEAD(4) BD_CHUNK(2, S0) PHASE_TAIL issue4(ksrc,         S0);
  PHASE_HEAD(4) BD_CHUNK(3, S1) PHASE_TAIL issue4(ksrc + 16384, S1);
  PHASE_HEAD(4) AC_CHUNK(0, S0) PHASE_TAIL issue4(ksrc + 32768, S0);
  PHASE_HEAD(4) AC_CHUNK(1, S1) PHASE_TAIL vload(0);
  PHASE_HEAD(4) AC_CHUNK(2, S0)

  // ---- softmax in registers ----
  #pragma unroll
  for (int t = 0; t < 24; ++t)
    #pragma unroll
    for (int j = 0; j < 4; ++j){
      int r = 16*w + g*4 + j, cc = t*16 + lr;
      accs[t][j] += b2f(*(const u16*)((const char*)SB + sb_off(r, cc)));
    }
  float mx[4] = {-1e30f,-1e30f,-1e30f,-1e30f};
  #pragma unroll
  for (int t = 0; t < 24; ++t)
    #pragma unroll
    for (int j = 0; j < 4; ++j) mx[j] = fmaxf(mx[j], accs[t][j]);
  #pragma unroll
  for (int j = 0; j < 4; ++j){
    mx[j] = fmaxf(mx[j], __shfl_xor(mx[j], 1));
    mx[j] = fmaxf(mx[j], __shfl_xor(mx[j], 2));
    mx[j] = fmaxf(mx[j], __shfl_xor(mx[j], 4));
    mx[j] = fmaxf(mx[j], __shfl_xor(mx[j], 8));
  }
  float sm[4] = {0.f,0.f,0.f,0.f};
  #pragma unroll
  for (int t = 0; t < 24; ++t)
    #pragma unroll
    for (int j = 0; j < 4; ++j){
      accs[t][j] = __expf((accs[t][j] - mx[j]) * 0.125f);
      sm[j] += accs[t][j];
    }
  #pragma unroll
  for (int j = 0; j < 4; ++j){
    sm[j] += __shfl_xor(sm[j], 1);
    sm[j] += __shfl_xor(sm[j], 2);
    sm[j] += __shfl_xor(sm[j], 4);
    sm[j] += __shfl_xor(sm[j], 8);
    sm[j] = 1.f / sm[j];
  }
  #pragma unroll
  for (int t = 0; t < 24; ++t)
    #pragma unroll
    for (int j = 0; j < 4; ++j){
      int r = 16*w + g*4 + j, cc = t*16 + lr;
      *(u16*)((char*)SB + sb_off(r, cc)) = f2b(accs[t][j] * sm[j]);
    }

  asm volatile("s_waitcnt vmcnt(0)" ::: "memory");
  SB0;
  vtwrite(S1);
  vload(1);
  VT_TAIL

  PV_CHUNK(0, S1)
  asm volatile("s_waitcnt vmcnt(0)" ::: "memory");
  SB0;
  vtwrite(S0);
  vload(2);
  VT_TAIL

  PV_CHUNK(1, S0)
  asm volatile("s_waitcnt vmcnt(0)" ::: "memory");
  SB0;
  vtwrite(S1);
  VT_TAIL

  PV_CHUNK(2, S1)

  #pragma unroll
  for (int n = 0; n < 4; ++n)
    #pragma unroll
    for (int j = 0; j < 4; ++j){
      int r = 16*w + g*4 + j;
      int t = c*64 + r, d = n*16 + lr;
      xout[((size_t)b*T1 + t)*1024 + h*64 + d] = f2b(acco[n][j]);
    }
}

// ---------------- launch ----------------
extern "C" void kernel_launch(void* const* d_in, const int* in_sizes, int n_in,
                              void* d_out, int out_size, void* d_ws, size_t ws_size,
                              hipStream_t stream)
{
  const float* query = (const float*)d_in[0];
  const float* key   = (const float*)d_in[1];
  const float* value = (const float*)d_in[2];
  const float* pos   = (const float*)d_in[3];
  const float* Wq  = (const float*)d_in[4];
  const float* bq  = (const float*)d_in[5];
  const float* Wk  = (const float*)d_in[6];
  const float* bk  = (const float*)d_in[7];
  const float* Wv  = (const float*)d_in[8];
  const float* bv  = (const float*)d_in[9];
  const float* Wp  = (const float*)d_in[10];
  const float* Wo  = (const float*)d_in[11];
  const float* bo  = (const float*)d_in[12];
  const float* pbu = (const float*)d_in[13];
  const float* pbv = (const float*)d_in[14];

  float* out   = (float*)d_out;
  float* cache = out + 2097152;

  u16* ws     = (u16*)d_ws;
  u16* Wq_bf  = ws + 9437184;
  u16* Wk_bf  = ws + 10485760;
  u16* Wv_bf  = ws + 11534336;
  u16* Wp_bf  = ws + 12582912;
  u16* Wo_bf  = ws + 13631488;
  u16* qu_bf  = ws + 14680064;
  u16* qv_bf  = ws + 16777216;
  u16* katt   = ws + 18874368;
  u16* vatt   = ws + 22282240;
  u16* patt   = ws + 25690112;
  u16* x_bf   = ws + 26148864;

  CvtArgs ca;
  ca.s[0] = { Wq, Wq_bf, 1024 };
  ca.s[1] = { Wk, Wk_bf, 1024 };
  ca.s[2] = { Wv, Wv_bf, 1024 };
  ca.s[3] = { Wp, Wp_bf, 1024 };
  ca.s[4] = { Wo, Wo_bf, 1024 };
  cvt_all<<<5120, 256, 0, stream>>>(ca);

  G4Args ga;
  ga.q = query; ga.k = key; ga.v = value; ga.p = pos + 448*1024;
  ga.Wq = Wq_bf; ga.Wk = Wk_bf; ga.Wv = Wv_bf; ga.Wp = Wp_bf;
  ga.bq = bq; ga.bk = bk; ga.bv = bv; ga.pbu = pbu; ga.pbv = pbv;
  ga.qu = qu_bf; ga.qv2 = qv_bf; ga.katt = katt; ga.vatt = vatt; ga.patt = patt;
  ga.cache = cache;
  gemm4<<<576, 256, 0, stream>>>(ga);

  attn_v3<<<512, 256, 0, stream>>>(qu_bf, qv_bf, katt, vatt, patt, x_bf);

  gemm_out<<<256, 256, 0, stream>>>(x_bf, Wo_bf, bo, out);
}